// Round 11
// baseline (714.864 us; speedup 1.0000x reference)
//
#include <hip/hip_runtime.h>
#include <hip/hip_bf16.h>

// DIEN (DIN_V2_Gru_Vec_attGru) forward. B=512, T=200, D=128, H=128.
// Round 11: MFMA GRU v2 — r8's mfma_f32_16x16x32_f16 recurrence body with
// 2 batch rows per block (256 blocks, 1/CU): fixes r8's 32-block parallelism
// failure while keeping MFMA's low LDS writeback (4 b128/lane vs 24 —
// r10's diagnosed bottleneck). Rows 2-15 of the M=16 tile stay zero; all
// scalar epilogues/writes guarded to rows<2. Rest identical to r10 (647us).

typedef __attribute__((ext_vector_type(8))) short bf16x8;
typedef __attribute__((ext_vector_type(4))) float f32x4;
typedef _Float16 f16x8 __attribute__((ext_vector_type(8)));

#define NC 4
#define TC 50
#define CROWS 25600          // TC*512 rows per chunk
#define CSH 3276800          // CROWS*128 shorts per chunk (rnn1/h1/XhA)
#define NGRU 256             // GRU blocks (2 rows each)

static __device__ __forceinline__ unsigned short f2bf(float f) {
  union { __hip_bfloat16 h; unsigned short u; } v;
  v.h = __float2bfloat16(f);
  return v.u;
}
static __device__ __forceinline__ float bf2f(unsigned short u) {
  union { __hip_bfloat16 h; unsigned short u; } v;
  v.u = u;
  return __bfloat162float(v.h);
}
static __device__ __forceinline__ unsigned short f2h(float f) {
  union { _Float16 h; unsigned short u; } v;
  v.h = (_Float16)f;
  return v.u;
}
static __device__ __forceinline__ float h2f(unsigned short u) {
  union { unsigned short u; _Float16 h; } v;
  v.u = u;
  return (float)v.h;
}
// LDS-only barrier: does NOT drain vmcnt (global prefetches stay in flight).
static __device__ __forceinline__ void gbar() {
  __builtin_amdgcn_sched_barrier(0);
  asm volatile("s_waitcnt lgkmcnt(0)" ::: "memory");
  __builtin_amdgcn_s_barrier();
  __builtin_amdgcn_sched_barrier(0);
}

// ---------------------------------------------------------------- prep
__global__ __launch_bounds__(256) void prep_weights(
    const float* __restrict__ item_eb,
    const float* __restrict__ Wg1, const float* __restrict__ Wc1,
    const float* __restrict__ Wg2, const float* __restrict__ Wc2,
    const float* __restrict__ aw1, const float* __restrict__ aw2,
    const float* __restrict__ aw3,
    const float* __restrict__ bg1, const float* __restrict__ bc1,
    const float* __restrict__ bg2, const float* __restrict__ bc2,
    const float* __restrict__ ab1, const float* __restrict__ ab2,
    unsigned short* __restrict__ W1xT, unsigned short* __restrict__ W2xT,
    unsigned short* __restrict__ AW1T, unsigned short* __restrict__ AW2T,
    float* __restrict__ b384_1, float* __restrict__ b384_2,
    float* __restrict__ bA1, float* __restrict__ bA2,
    unsigned short* __restrict__ WghT1, unsigned short* __restrict__ WchT1,
    unsigned short* __restrict__ WghT2, unsigned short* __restrict__ WchT2,
    float* __restrict__ w3p, unsigned short* __restrict__ Xq,
    float* __restrict__ hstate)
{
  int e = blockIdx.x * 256 + threadIdx.x;
  if (e < 49152) {              // W1xT/W2xT: [384 n][128 k]
    int n = e >> 7, k = e & 127;
    float v1 = (n < 256) ? Wg1[k * 256 + n] : Wc1[k * 128 + (n - 256)];
    float v2 = (n < 256) ? Wg2[k * 256 + n] : Wc2[k * 128 + (n - 256)];
    W1xT[e] = f2bf(v1);
    W2xT[e] = f2bf(v2);
  }
  if (e < 65536) {              // AW1T: [128 n][512 k], pad n>=80
    int n = e >> 9, k = e & 511;
    AW1T[e] = f2bf(n < 80 ? aw1[k * 80 + n] : 0.f);
    Xq[e] = f2bf(item_eb[e]);   // bf16 item_eb [512][128]
    hstate[e] = 0.f;
  }
  if (e < 16384) {              // AW2T: [128 n][128 k]
    int n = e >> 7, k = e & 127;
    AW2T[e] = f2bf((n < 40 && k < 80) ? aw2[k * 40 + n] : 0.f);
  }
  if (e < 32768) {              // WghT: [256 n][128 k] f16 (h-part of Wg)
    int n = e >> 7, k = e & 127;
    WghT1[e] = f2h(Wg1[(128 + k) * 256 + n]);
    WghT2[e] = f2h(Wg2[(128 + k) * 256 + n]);
  }
  if (e < 16384) {              // WchT: [128 n][128 k] f16 (h-part of Wc)
    int n = e >> 7, k = e & 127;
    WchT1[e] = f2h(Wc1[(128 + k) * 128 + n]);
    WchT2[e] = f2h(Wc2[(128 + k) * 128 + n]);
  }
  if (e < 384) {
    b384_1[e] = (e < 256) ? bg1[e] : bc1[e - 256];
    b384_2[e] = (e < 256) ? bg2[e] : bc2[e - 256];
  }
  if (e < 128) {
    bA1[e] = (e < 80) ? ab1[e] : 0.f;
    bA2[e] = (e < 40) ? ab2[e] : 0.f;
    w3p[e] = (e < 40) ? aw3[e] : 0.f;
  }
}

// ---------------------------------------------------------------- cast his -> bf16 t-major
__global__ __launch_bounds__(256) void cast_his_t(const float4* __restrict__ in4,
                                                  ushort4* __restrict__ out4)
{
  int i = blockIdx.x * 256 + threadIdx.x;
  float4 v = in4[i];
  int d4 = (i & 31) << 2;
  int bt = i >> 5;
  int tt = bt % 200, bb = bt / 200;
  out4[(((size_t)tt * 512 + bb) * 128 + d4) >> 2] =
      make_ushort4(f2bf(v.x), f2bf(v.y), f2bf(v.z), f2bf(v.w));
}

// ---------------------------------------------------------------- gemm body
// SRC 0: plain bf16 A. SRC 1: din on-the-fly [q|r|q-r|q*r], K=512.
// EPI 0: f16 out (+bias). EPI 1: bf16 sigmoid out. EPI 2: sigmoid+scorer->scores.
struct GemmP {
  const unsigned short* A;
  const unsigned short* B;
  const float* bias;
  unsigned short* out;
  float* scores;
  const float* w3p;
  const float* b3;
  const unsigned short* Xq;
  const unsigned short* rnn1;
  long rowbase;
  int K, ldc, mtiles, tbase;
};

static __device__ __forceinline__ uint4 bfop(uint4 q, uint4 r, bool mul) {
  unsigned short* qs = (unsigned short*)&q;
  unsigned short* rs = (unsigned short*)&r;
  uint4 o;
  unsigned short* os = (unsigned short*)&o;
#pragma unroll
  for (int i = 0; i < 8; i++) {
    float a = bf2f(qs[i]), b = bf2f(rs[i]);
    os[i] = f2bf(mul ? a * b : a - b);
  }
  return o;
}

template <int SRC, int EPI>
__device__ __forceinline__ void gemm_body(const GemmP& P, int tile, char* smem) {
  uint4* AsB = (uint4*)smem;         // 16 KB
  uint4* BsB = AsB + 1024;           // 16 KB
  const int tid = threadIdx.x;
  const int w = tid >> 6, l = tid & 63;
  const int mb = tile % P.mtiles, nb = tile / P.mtiles;
  const long mBase = (long)mb * 128;
  const int nBase = nb * 128;

  f32x4 acc[2][8];
#pragma unroll
  for (int m = 0; m < 2; m++)
#pragma unroll
    for (int n = 0; n < 8; n++) acc[m][n] = 0.f;

  const int srow = (tid >> 3) & 31;
  const int scc = l & 7;
  const int KK = SRC ? 512 : P.K;

  for (int kb = 0; kb < KK; kb += 64) {
#pragma unroll
    for (int p = 0; p < 4; p++) {
      int row = p * 32 + srow;
      long grow = mBase + row;
      uint4 va;
      if (SRC == 0) {
        va = *(const uint4*)(P.A + (size_t)grow * KK + kb + scc * 8);
      } else {
        int seg = kb >> 7;
        int c0 = (kb & 127) + scc * 8;
        int b = (int)(grow & 511);
        if (seg == 0) {
          va = *(const uint4*)(P.Xq + b * 128 + c0);
        } else if (seg == 1) {
          va = *(const uint4*)(P.rnn1 + (size_t)(P.rowbase + grow) * 128 + c0);
        } else {
          uint4 vq = *(const uint4*)(P.Xq + b * 128 + c0);
          uint4 vr = *(const uint4*)(P.rnn1 + (size_t)(P.rowbase + grow) * 128 + c0);
          va = bfop(vq, vr, seg == 3);
        }
      }
      uint4 vb = *(const uint4*)(P.B + (size_t)(nBase + row) * KK + kb + scc * 8);
      AsB[row * 8 + (scc ^ (row & 7))] = va;
      BsB[row * 8 + (scc ^ (row & 7))] = vb;
    }
    __syncthreads();
#pragma unroll
    for (int ks = 0; ks < 2; ks++) {
      int ccr = ks * 4 + (l >> 4);
      int r0 = w * 32 + (l & 15);
      int r1 = r0 + 16;
      bf16x8 a0 = *(const bf16x8*)&AsB[r0 * 8 + (ccr ^ (r0 & 7))];
      bf16x8 a1 = *(const bf16x8*)&AsB[r1 * 8 + (ccr ^ (r1 & 7))];
#pragma unroll
      for (int n = 0; n < 8; n++) {
        int rb = n * 16 + (l & 15);
        bf16x8 bn = *(const bf16x8*)&BsB[rb * 8 + (ccr ^ (rb & 7))];
        acc[0][n] = __builtin_amdgcn_mfma_f32_16x16x32_bf16(a0, bn, acc[0][n], 0, 0, 0);
        acc[1][n] = __builtin_amdgcn_mfma_f32_16x16x32_bf16(a1, bn, acc[1][n], 0, 0, 0);
      }
    }
    __syncthreads();
  }

  const int lcol = l & 15, lrow4 = (l >> 4) * 4;
  if (EPI == 2) {
    float sp[2][4] = {{0.f, 0.f, 0.f, 0.f}, {0.f, 0.f, 0.f, 0.f}};
#pragma unroll
    for (int n = 0; n < 8; n++) {
      int gcol = n * 16 + lcol;
      float bb = P.bias[gcol];
      float w3 = P.w3p[gcol];
#pragma unroll
      for (int m = 0; m < 2; m++)
#pragma unroll
        for (int i = 0; i < 4; i++) {
          float v = acc[m][n][i] + bb;
          sp[m][i] += w3 / (1.f + __expf(-v));
        }
    }
#pragma unroll
    for (int msk = 1; msk < 16; msk <<= 1)
#pragma unroll
      for (int m = 0; m < 2; m++)
#pragma unroll
        for (int i = 0; i < 4; i++) sp[m][i] += __shfl_xor(sp[m][i], msk);
    float b3v = P.b3[0];
    if (lcol == 0) {
#pragma unroll
      for (int m = 0; m < 2; m++)
#pragma unroll
        for (int i = 0; i < 4; i++) {
          long grow = mBase + w * 32 + m * 16 + lrow4 + i;
          int b = (int)(grow & 511);
          int tp = (int)(grow >> 9) + P.tbase;
          P.scores[b * 200 + tp] = sp[m][i] + b3v;
        }
    }
  } else {
#pragma unroll
    for (int n = 0; n < 8; n++) {
      int gcol = nBase + n * 16 + lcol;
      float bb = P.bias[gcol];
#pragma unroll
      for (int m = 0; m < 2; m++)
#pragma unroll
        for (int i = 0; i < 4; i++) {
          long grow = mBase + w * 32 + m * 16 + lrow4 + i;
          float v = acc[m][n][i] + bb;
          if (EPI == 0) P.out[grow * P.ldc + gcol] = f2h(v);
          else          P.out[grow * P.ldc + gcol] = f2bf(1.f / (1.f + __expf(-v)));
        }
    }
  }
}

// ---------------------------------------------------------------- MFMA gru body
// Block owns 2 batch rows (M=16 tile, rows 2-15 zero). 4 waves; wave w owns
// pass1 N-tiles {w,4+w,8+w,12+w} (r cols 16w/64+16w, u cols 128+16w/192+16w)
// and pass2 tiles {w,4+w}. Scalar epilogues guarded to rows<2 (lanes hi==0).
struct GruP {
  const unsigned short* xproj;   // f16 [TC][512][384]
  const unsigned short* Wgh;     // f16 [256 n][128 k]
  const unsigned short* Wch;     // f16 [128 n][128 k]
  const int* seqlen;
  const float* alphas;
  unsigned short* outbf;         // bf16 [T][512][128] (GRU1 only)
  float* hstate;
  int tbase;
};

static __device__ __forceinline__ int swz(int row, int colByte) {
  return row * 256 + (colByte ^ ((row & 7) << 4));
}
static __device__ __forceinline__ float sigm(float x) {
  return 1.f / (1.f + __expf(-x));
}

template <int AUGRU>
__device__ void gru_body(const GruP& P, int rblk, char* smem) {
  const int t = threadIdx.x;
  const int w = t >> 6, l = t & 63;
  const int lo = l & 15, hi = l >> 4;
  const int b0 = rblk * 2;

  const int len0 = P.seqlen[b0], len1 = P.seqlen[b0 + 1];
  int mlen = len0 > len1 ? len0 : len1;
  int bsteps = mlen - P.tbase;
  if (bsteps > TC) bsteps = TC;

  if (bsteps <= 0) {
    if (!AUGRU && t < 128) {
      for (int s = 0; s < TC; s++)
        ((unsigned int*)(P.outbf + ((size_t)(P.tbase + s) * 512 + b0) * 128))[t] = 0;
    }
    return;
  }
  __builtin_amdgcn_s_setprio(1);

  // weight B-fragments (f16), loaded once
  f16x8 wg[4][4], wc[2][4];
#pragma unroll
  for (int n = 0; n < 4; n++) {
    int nt = w + n * 4;
#pragma unroll
    for (int ck = 0; ck < 4; ck++)
      wg[n][ck] = *(const f16x8*)(P.Wgh + (nt * 16 + lo) * 128 + ck * 32 + hi * 8);
  }
#pragma unroll
  for (int n = 0; n < 2; n++) {
    int nt = w + n * 4;
#pragma unroll
    for (int ck = 0; ck < 4; ck++)
      wc[n][ck] = *(const f16x8*)(P.Wch + (nt * 16 + lo) * 128 + ck * 32 + hi * 8);
  }

  char* hL = smem;            // f16 [16][128] swizzled (4 KB)
  char* rL = smem + 4096;     // f16 [16][128] swizzled (4 KB)

  // zero both tiles (rows 2-15 stay zero forever)
  ((uint4*)hL)[t] = make_uint4(0, 0, 0, 0);
  ((uint4*)rL)[t] = make_uint4(0, 0, 0, 0);
  __syncthreads();

  const int colc0 = w * 16 + lo, colc1 = 64 + w * 16 + lo;
  float hreg[2][2];           // [colgroup j][row i], rows 0..1 (lanes hi==0)
  if (hi == 0) {
#pragma unroll
    for (int i = 0; i < 2; i++) {
      float h0 = P.hstate[(b0 + i) * 128 + colc0];
      float h1 = P.hstate[(b0 + i) * 128 + colc1];
      hreg[0][i] = h0;
      hreg[1][i] = h1;
      *(unsigned short*)(hL + swz(i, colc0 * 2)) = f2h(h0);
      *(unsigned short*)(hL + swz(i, colc1 * 2)) = f2h(h1);
    }
  }
  gbar();

  const unsigned short* xp = P.xproj;
  const size_t RS = (size_t)512 * 384;

  for (int ts = 0; ts < bsteps; ++ts) {
    // issue this step's preact/alpha loads early (hide under ds_read+MFMA)
    unsigned short xgs[4][2], xcs[2][2];
    float al[2];
#pragma unroll
    for (int i = 0; i < 2; i++) {
      size_t rb = (size_t)ts * RS + (size_t)(b0 + i) * 384;
      xgs[0][i] = xp[rb + 16 * w + lo];
      xgs[1][i] = xp[rb + 64 + 16 * w + lo];
      xgs[2][i] = xp[rb + 128 + 16 * w + lo];
      xgs[3][i] = xp[rb + 192 + 16 * w + lo];
      xcs[0][i] = xp[rb + 256 + 16 * w + lo];
      xcs[1][i] = xp[rb + 320 + 16 * w + lo];
      if (AUGRU) al[i] = P.alphas[(b0 + i) * 200 + P.tbase + ts];
    }

    // ---- pass1: gates = h @ WghT (16 MFMA/wave, rows>=2 contribute zero)
    f16x8 aF[4];
#pragma unroll
    for (int ck = 0; ck < 4; ck++)
      aF[ck] = *(const f16x8*)(hL + swz(lo, ck * 64 + hi * 16));
    f32x4 acc1[4];
#pragma unroll
    for (int n = 0; n < 4; n++) {
      acc1[n] = 0.f;
#pragma unroll
      for (int ck = 0; ck < 4; ck++)
        acc1[n] = __builtin_amdgcn_mfma_f32_16x16x32_f16(aF[ck], wg[n][ck], acc1[n], 0, 0, 0);
    }
    float uu[2][2];
    if (hi == 0) {
#pragma unroll
      for (int i = 0; i < 2; i++) {
        float r0 = sigm(acc1[0][i] + h2f(xgs[0][i]));
        float r1 = sigm(acc1[1][i] + h2f(xgs[1][i]));
        *(unsigned short*)(rL + swz(i, colc0 * 2)) = f2h(r0 * hreg[0][i]);
        *(unsigned short*)(rL + swz(i, colc1 * 2)) = f2h(r1 * hreg[1][i]);
        uu[0][i] = sigm(acc1[2][i] + h2f(xgs[2][i]));
        uu[1][i] = sigm(acc1[3][i] + h2f(xgs[3][i]));
      }
    }
    gbar();

    // ---- pass2: cand = (r*h) @ WchT (8 MFMA/wave)
    f16x8 rF[4];
#pragma unroll
    for (int ck = 0; ck < 4; ck++)
      rF[ck] = *(const f16x8*)(rL + swz(lo, ck * 64 + hi * 16));
    f32x4 acc2[2];
#pragma unroll
    for (int n = 0; n < 2; n++) {
      acc2[n] = 0.f;
#pragma unroll
      for (int ck = 0; ck < 4; ck++)
        acc2[n] = __builtin_amdgcn_mfma_f32_16x16x32_f16(rF[ck], wc[n][ck], acc2[n], 0, 0, 0);
    }
    if (hi == 0) {
#pragma unroll
      for (int i = 0; i < 2; i++) {
        bool valid = (P.tbase + ts) < (i ? len1 : len0);
#pragma unroll
        for (int j = 0; j < 2; j++) {
          int col = j ? colc1 : colc0;
          float c = acc2[j][i] + h2f(xcs[j][i]);
          c = fminf(fmaxf(c, -15.f), 15.f);
          float e2 = __expf(2.f * c);
          c = 1.f - 2.f / (e2 + 1.f);          // tanh
          float u = uu[j][i];
          if (AUGRU) u *= (1.f - al[i]);
          float hn = u * hreg[j][i] + (1.f - u) * c;
          hn = valid ? hn : hreg[j][i];
          hreg[j][i] = hn;
          *(unsigned short*)(hL + swz(i, col * 2)) = f2h(hn);
          if (!AUGRU)
            P.outbf[((size_t)(P.tbase + ts) * 512 + b0 + i) * 128 + col] =
                valid ? f2bf(hn) : (unsigned short)0;
        }
      }
    }
    gbar();
  }

  if (hi == 0) {
#pragma unroll
    for (int i = 0; i < 2; i++) {
      P.hstate[(b0 + i) * 128 + colc0] = hreg[0][i];
      P.hstate[(b0 + i) * 128 + colc1] = hreg[1][i];
    }
  }
  if (!AUGRU && t < 128) {
    for (int s = bsteps; s < TC; s++)
      ((unsigned int*)(P.outbf + ((size_t)(P.tbase + s) * 512 + b0) * 128))[t] = 0;
  }
}

// ---------------------------------------------------------------- his_sum body
__device__ void hsum_body(const float* __restrict__ his, float* __restrict__ hs,
                          const int* __restrict__ seqlen, int b, char* smem) {
  float* sm = (float*)smem;
  int t = threadIdx.x;
  int len = seqlen[b];
  int col = t & 127, hf = t >> 7;
  float s = 0.f;
  for (int ts = hf; ts < len; ts += 2) s += his[((size_t)b * 200 + ts) * 128 + col];
  sm[t] = s;
  __syncthreads();
  if (t < 128) hs[b * 128 + t] = sm[t] + sm[t + 128];
}

// ---------------------------------------------------------------- fat kernel
template <int AUG, int GRU, int S1, int E1, int S2, int E2, int S3, int E3, int HS>
__global__ __launch_bounds__(256) void fatk(GruP gp, GemmP p1, int c1,
                                            GemmP p2, int c2, GemmP p3,
                                            const float* hisp, float* hsp)
{
  extern __shared__ char smem[];
  int id = blockIdx.x;
  if constexpr (GRU) {
    if (id < NGRU) { gru_body<AUG>(gp, id, smem); return; }
    id -= NGRU;
  }
  if constexpr (HS) {
    if (id < 512) { hsum_body(hisp, hsp, gp.seqlen, id, smem); return; }
    id -= 512;
  }
  if constexpr (S1 >= 0) {
    if (id < c1) { gemm_body<S1, E1>(p1, id, smem); return; }
    id -= c1;
  }
  if constexpr (S2 >= 0) {
    if (id < c2) { gemm_body<S2, E2>(p2, id, smem); return; }
    id -= c2;
  }
  if constexpr (S3 >= 0) gemm_body<S3, E3>(p3, id, smem);
}

// ---------------------------------------------------------------- masked softmax (+zero hstate)
__global__ __launch_bounds__(256) void mask_softmax(
    const float* __restrict__ scores, const int* __restrict__ seqlen,
    float* __restrict__ alphas, float* __restrict__ hstate)
{
  int b = blockIdx.x, t = threadIdx.x;
  __shared__ float red[256];
  if (t < 128) hstate[b * 128 + t] = 0.f;
  int len = seqlen[b];
  float s = (t < 200 && t < len) ? scores[b * 200 + t] : -1e30f;
  red[t] = s;
  __syncthreads();
  for (int o = 128; o > 0; o >>= 1) {
    if (t < o) red[t] = fmaxf(red[t], red[t + o]);
    __syncthreads();
  }
  float m = red[0];
  __syncthreads();
  float e = (t < 200 && t < len) ? __expf(s - m) : 0.f;
  red[t] = e;
  __syncthreads();
  for (int o = 128; o > 0; o >>= 1) {
    if (t < o) red[t] += red[t + o];
    __syncthreads();
  }
  float denom = red[0];
  if (t < 200) alphas[b * 200 + t] = e / denom;
}

// ---------------------------------------------------------------- head (his_sum precomputed)
__global__ __launch_bounds__(256) void head_kernel(
    const float* __restrict__ item_eb, const float* __restrict__ hs,
    const float* __restrict__ hstate,
    const float* __restrict__ w1, const float* __restrict__ b1, const float* __restrict__ a1,
    const float* __restrict__ w2, const float* __restrict__ b2, const float* __restrict__ a2,
    const float* __restrict__ w3, const float* __restrict__ b3,
    float* __restrict__ out)
{
  int b = blockIdx.x, t = threadIdx.x;
  __shared__ float frow[512];
  __shared__ float z1[200];
  __shared__ float z2[80];
  if (t < 128) {
    float sv = hs[b * 128 + t];
    float q = item_eb[b * 128 + t];
    frow[t] = q;
    frow[128 + t] = sv;
    frow[256 + t] = q * sv;
    frow[384 + t] = hstate[b * 128 + t];
  }
  __syncthreads();
  if (t < 200) {
    float acc = b1[t];
#pragma unroll 8
    for (int k = 0; k < 512; k++) acc += frow[k] * w1[k * 200 + t];
    z1[t] = acc > 0.f ? acc : a1[t] * acc;
  }
  __syncthreads();
  if (t < 80) {
    float acc = b2[t];
#pragma unroll 8
    for (int k = 0; k < 200; k++) acc += z1[k] * w2[k * 80 + t];
    z2[t] = acc > 0.f ? acc : a2[t] * acc;
  }
  __syncthreads();
  if (t == 0) {
    float l0 = b3[0], l1 = b3[1];
    for (int k = 0; k < 80; k++) {
      float z = z2[k];
      l0 += z * w3[k * 2];
      l1 += z * w3[k * 2 + 1];
    }
    float m = fmaxf(l0, l1);
    float e0 = __expf(l0 - m), e1 = __expf(l1 - m);
    out[b * 2 + 0] = e0 / (e0 + e1);
    out[b * 2 + 1] = e1 / (e0 + e1);
  }
}

// ---------------------------------------------------------------- launch
extern "C" void kernel_launch(void* const* d_in, const int* in_sizes, int n_in,
                              void* d_out, int out_size, void* d_ws, size_t ws_size,
                              hipStream_t stream)
{
  const float* item_eb = (const float*)d_in[0];
  const float* his     = (const float*)d_in[1];
  const float* Wg1     = (const float*)d_in[2];
  const float* bg1     = (const float*)d_in[3];
  const float* Wc1     = (const float*)d_in[4];
  const float* bc1     = (const float*)d_in[5];
  const float* aw1     = (const float*)d_in[6];
  const float* ab1     = (const float*)d_in[7];
  const float* aw2     = (const float*)d_in[8];
  const float* ab2     = (const float*)d_in[9];
  const float* aw3     = (const float*)d_in[10];
  const float* ab3     = (const float*)d_in[11];
  const float* Wg2     = (const float*)d_in[12];
  const float* bg2     = (const float*)d_in[13];
  const float* Wc2     = (const float*)d_in[14];
  const float* bc2     = (const float*)d_in[15];
  const float* fc1w    = (const float*)d_in[16];
  const float* fc1b    = (const float*)d_in[17];
  const float* al1     = (const float*)d_in[18];
  const float* fc2w    = (const float*)d_in[19];
  const float* fc2b    = (const float*)d_in[20];
  const float* al2     = (const float*)d_in[21];
  const float* fc3w    = (const float*)d_in[22];
  const float* fc3b    = (const float*)d_in[23];
  const int*   seqlen  = (const int*)d_in[24];

  // ---- workspace layout (~93.5 MB; round-2 proved >=94.24 MB available)
  char* ws = (char*)d_ws;
  unsigned short* XhA    = (unsigned short*)(ws + 0L);         // 26,214,400 his bf16 t-major; later h1 ring
  unsigned short* xpA    = (unsigned short*)(ws + 26214400L);  // 19,660,800 f16 xproj buf A
  unsigned short* xpB    = (unsigned short*)(ws + 45875200L);  // 19,660,800 f16 xproj buf B
  unsigned short* rnn1   = (unsigned short*)(ws + 65536000L);  // 26,214,400
  float*          scores = (float*)(ws + 91750400L);           //    409,600 (hs after softmax)
  float*          alphas = (float*)(ws + 92160000L);           //    409,600
  float*          hstate = (float*)(ws + 92569600L);           //    262,144
  unsigned short* WghT1  = (unsigned short*)(ws + 92831744L);  //     65,536
  unsigned short* WchT1  = (unsigned short*)(ws + 92897280L);  //     32,768
  unsigned short* WghT2  = (unsigned short*)(ws + 92930048L);  //     65,536
  unsigned short* WchT2  = (unsigned short*)(ws + 92995584L);  //     32,768
  unsigned short* W1xT   = (unsigned short*)(ws + 93028352L);  //     98,304
  unsigned short* W2xT   = (unsigned short*)(ws + 93126656L);  //     98,304
  unsigned short* AW1T   = (unsigned short*)(ws + 93224960L);  //    131,072
  unsigned short* AW2T   = (unsigned short*)(ws + 93356032L);  //     32,768
  float*          b384_1 = (float*)(ws + 93388800L);           //      1,536
  float*          b384_2 = (float*)(ws + 93390336L);           //      1,536
  float*          bA1    = (float*)(ws + 93391872L);           //        512
  float*          bA2    = (float*)(ws + 93392384L);           //        512
  float*          w3p    = (float*)(ws + 93392896L);           //        512
  unsigned short* Xq     = (unsigned short*)(ws + 93393408L);  //    131,072
  float*          hs     = scores;                             // reuse after softmax

  unsigned short* h1[NC] = {XhA, XhA + CSH, XhA + 2 * CSH, XhA + 3 * CSH};

  const int SM = 32768;
  GruP gz{}; GemmP dz{};
  gz.seqlen = seqlen;

  auto mkGru = [&](int c, int aug) {
    GruP g;
    g.xproj = (c & 1) ? xpB : xpA;
    g.Wgh = aug ? WghT2 : WghT1;
    g.Wch = aug ? WchT2 : WchT1;
    g.seqlen = seqlen; g.alphas = alphas;
    g.outbf = aug ? nullptr : rnn1; g.hstate = hstate; g.tbase = c * TC;
    return g;
  };
  auto mkXp = [&](const unsigned short* A, const float* bias, unsigned short* outp) {
    GemmP p{}; p.A = A; p.B = (bias == b384_1) ? W1xT : W2xT; p.bias = bias;
    p.out = outp; p.K = 128; p.ldc = 384; p.mtiles = 200; return p;
  };
  auto mkAtt1 = [&](int c) {
    GemmP p{}; p.B = AW1T; p.bias = bA1; p.out = h1[c];
    p.Xq = Xq; p.rnn1 = rnn1; p.rowbase = (long)c * CROWS;
    p.K = 512; p.ldc = 128; p.mtiles = 200; return p;
  };
  auto mkAtt2 = [&](int c) {
    GemmP p{}; p.A = h1[c]; p.B = AW2T; p.bias = bA2;
    p.scores = scores; p.w3p = w3p; p.b3 = ab3;
    p.K = 128; p.ldc = 128; p.mtiles = 200; p.tbase = c * TC; return p;
  };

  // L1/L2: prep + cast
  prep_weights<<<256, 256, 0, stream>>>(item_eb, Wg1, Wc1, Wg2, Wc2, aw1, aw2, aw3,
                                        bg1, bc1, bg2, bc2, ab1, ab2,
                                        W1xT, W2xT, AW1T, AW2T, b384_1, b384_2, bA1, bA2,
                                        WghT1, WchT1, WghT2, WchT2, w3p, Xq, hstate);
  cast_his_t<<<12800, 256, 0, stream>>>((const float4*)his, (ushort4*)XhA);

  // L3: xproj1-c0 -> xpA
  fatk<0,0, 0,0, -1,0, -1,0, 0><<<600, 256, SM, stream>>>(
      gz, mkXp(XhA, b384_1, xpA), 600, dz, 0, dz, nullptr, nullptr);
  // L4: gru1-c0 | xproj1-c1 -> xpB
  fatk<0,1, 0,0, -1,0, -1,0, 0><<<856, 256, SM, stream>>>(
      mkGru(0,0), mkXp(XhA + (size_t)CSH, b384_1, xpB), 600, dz, 0, dz, nullptr, nullptr);
  // L5: gru1-c1 | xproj1-c2 -> xpA
  fatk<0,1, 0,0, -1,0, -1,0, 0><<<856, 256, SM, stream>>>(
      mkGru(1,0), mkXp(XhA + (size_t)2*CSH, b384_1, xpA), 600, dz, 0, dz, nullptr, nullptr);
  // L6: gru1-c2 | xproj1-c3 -> xpB | att1-c0 -> h1[0]
  fatk<0,1, 0,0, 1,1, -1,0, 0><<<1056, 256, SM, stream>>>(
      mkGru(2,0), mkXp(XhA + (size_t)3*CSH, b384_1, xpB), 600, mkAtt1(0), 200, dz, nullptr, nullptr);
  // L7: gru1-c3 | att1-c1 | att2-c0
  fatk<0,1, 1,1, 0,2, -1,0, 0><<<656, 256, SM, stream>>>(
      mkGru(3,0), mkAtt1(1), 200, mkAtt2(0), 200, dz, nullptr, nullptr);
  // L8: att1-c2 | att2-c1 | augru-gemm-c0 -> xpA
  fatk<0,0, 1,1, 0,2, 0,0, 0><<<1000, 256, SM, stream>>>(
      gz, mkAtt1(2), 200, mkAtt2(1), 200, mkXp(rnn1, b384_2, xpA), nullptr, nullptr);
  // L9: att1-c3 | att2-c2 | augru-gemm-c1 -> xpB
  fatk<0,0, 1,1, 0,2, 0,0, 0><<<1000, 256, SM, stream>>>(
      gz, mkAtt1(3), 200, mkAtt2(2), 200, mkXp(rnn1 + (size_t)CSH, b384_2, xpB), nullptr, nullptr);
  // L10: att2-c3
  fatk<0,0, 0,2, -1,0, -1,0, 0><<<200, 256, SM, stream>>>(
      gz, mkAtt2(3), 200, dz, 0, dz, nullptr, nullptr);
  // L11: softmax + zero hstate
  mask_softmax<<<512, 256, 0, stream>>>(scores, seqlen, alphas, hstate);
  // L12: augru-c0 | his_sum backfill
  fatk<1,1, -1,0, -1,0, -1,0, 1><<<768, 256, SM, stream>>>(
      mkGru(0,1), dz, 0, dz, 0, dz, his, hs);
  // L13: augru-c1 | augru-gemm-c2 -> xpA
  fatk<1,1, 0,0, -1,0, -1,0, 0><<<856, 256, SM, stream>>>(
      mkGru(1,1), mkXp(rnn1 + (size_t)2*CSH, b384_2, xpA), 600, dz, 0, dz, nullptr, nullptr);
  // L14: augru-c2 | augru-gemm-c3 -> xpB
  fatk<1,1, 0,0, -1,0, -1,0, 0><<<856, 256, SM, stream>>>(
      mkGru(2,1), mkXp(rnn1 + (size_t)3*CSH, b384_2, xpB), 600, dz, 0, dz, nullptr, nullptr);
  // L15: augru-c3
  fatk<1,1, -1,0, -1,0, -1,0, 0><<<NGRU, 256, SM, stream>>>(
      mkGru(3,1), dz, 0, dz, 0, dz, nullptr, nullptr);
  // L16: head
  head_kernel<<<512, 256, 0, stream>>>(item_eb, hs, hstate,
                                       fc1w, fc1b, al1, fc2w, fc2b, al2,
                                       fc3w, fc3b, (float*)d_out);
}

// Round 12
// 643.298 us; speedup vs baseline: 1.1112x; 1.1112x over previous
//
#include <hip/hip_runtime.h>
#include <hip/hip_bf16.h>

// DIEN (DIN_V2_Gru_Vec_attGru) forward. B=512, T=200, D=128, H=128.
// Round 12: r10 (best, 647us) + address_space(1) casts on all GRU global
// accesses. Theory: generic-pointer loads were emitted as flat_* (which
// count in BOTH vmcnt and lgkmcnt), so gbar()'s lgkmcnt(0) drained the
// x-preact prefetches at every barrier. Explicit global_* (vmcnt-only)
// lets prefetches survive barriers. No other change.

typedef __attribute__((ext_vector_type(8))) short bf16x8;
typedef __attribute__((ext_vector_type(4))) float f32x4;
typedef _Float16 f16x2 __attribute__((ext_vector_type(2)));

#define NC 4
#define TC 50
#define CROWS 25600          // TC*512 rows per chunk
#define CSH 3276800          // CROWS*128 shorts per chunk (rnn1/h1/XhA)

static __device__ __forceinline__ unsigned short f2bf(float f) {
  union { __hip_bfloat16 h; unsigned short u; } v;
  v.h = __float2bfloat16(f);
  return v.u;
}
static __device__ __forceinline__ float bf2f(unsigned short u) {
  union { __hip_bfloat16 h; unsigned short u; } v;
  v.u = u;
  return __bfloat162float(v.h);
}
static __device__ __forceinline__ unsigned short f2h(float f) {
  union { _Float16 h; unsigned short u; } v;
  v.h = (_Float16)f;
  return v.u;
}
static __device__ __forceinline__ float h2f(unsigned short u) {
  union { unsigned short u; _Float16 h; } v;
  v.u = u;
  return (float)v.h;
}
static __device__ __forceinline__ unsigned int pkf16(float a, float b) {
  union { f16x2 v; unsigned int u; } c;
  c.v = (f16x2){(_Float16)a, (_Float16)b};
  return c.u;
}
static __device__ __forceinline__ void dot2a(float& acc, unsigned int w, unsigned int h) {
  asm volatile("v_dot2_f32_f16 %0, %1, %2, %0" : "+v"(acc) : "v"(w), "v"(h));
}
// Guaranteed global (addrspace 1) accesses — vmcnt-only, never lgkmcnt.
static __device__ __forceinline__ unsigned short gld_u16(const unsigned short* p) {
  return *(const __attribute__((address_space(1))) unsigned short*)p;
}
static __device__ __forceinline__ float gld_f32(const float* p) {
  return *(const __attribute__((address_space(1))) float*)p;
}
static __device__ __forceinline__ void gst_u16(unsigned short* p, unsigned short v) {
  *(__attribute__((address_space(1))) unsigned short*)p = v;
}
static __device__ __forceinline__ void gst_u32(unsigned int* p, unsigned int v) {
  *(__attribute__((address_space(1))) unsigned int*)p = v;
}
static __device__ __forceinline__ void gst_f32(float* p, float v) {
  *(__attribute__((address_space(1))) float*)p = v;
}
// LDS-only barrier: does NOT drain vmcnt (global prefetches stay in flight).
static __device__ __forceinline__ void gbar() {
  __builtin_amdgcn_sched_barrier(0);
  asm volatile("s_waitcnt lgkmcnt(0)" ::: "memory");
  __builtin_amdgcn_s_barrier();
  __builtin_amdgcn_sched_barrier(0);
}

// ---------------------------------------------------------------- prep
__global__ __launch_bounds__(256) void prep_weights(
    const float* __restrict__ item_eb,
    const float* __restrict__ Wg1, const float* __restrict__ Wc1,
    const float* __restrict__ Wg2, const float* __restrict__ Wc2,
    const float* __restrict__ aw1, const float* __restrict__ aw2,
    const float* __restrict__ aw3,
    const float* __restrict__ bg1, const float* __restrict__ bc1,
    const float* __restrict__ bg2, const float* __restrict__ bc2,
    const float* __restrict__ ab1, const float* __restrict__ ab2,
    unsigned short* __restrict__ W1xT, unsigned short* __restrict__ W2xT,
    unsigned short* __restrict__ AW1T, unsigned short* __restrict__ AW2T,
    float* __restrict__ b384_1, float* __restrict__ b384_2,
    float* __restrict__ bA1, float* __restrict__ bA2,
    unsigned int* __restrict__ WgP1, unsigned int* __restrict__ WcP1,
    unsigned int* __restrict__ WgP2, unsigned int* __restrict__ WcP2,
    float* __restrict__ w3p, unsigned short* __restrict__ Xq,
    float* __restrict__ hstate)
{
  int e = blockIdx.x * 256 + threadIdx.x;
  if (e < 49152) {              // W1xT/W2xT: [384 n][128 k]
    int n = e >> 7, k = e & 127;
    float v1 = (n < 256) ? Wg1[k * 256 + n] : Wc1[k * 128 + (n - 256)];
    float v2 = (n < 256) ? Wg2[k * 256 + n] : Wc2[k * 128 + (n - 256)];
    W1xT[e] = f2bf(v1);
    W2xT[e] = f2bf(v2);
  }
  if (e < 65536) {              // AW1T: [128 n][512 k], pad n>=80
    int n = e >> 9, k = e & 511;
    AW1T[e] = f2bf(n < 80 ? aw1[k * 80 + n] : 0.f);
    Xq[e] = f2bf(item_eb[e]);   // bf16 item_eb [512][128]
    hstate[e] = 0.f;
  }
  if (e < 16384) {              // AW2T: [128 n][128 k]
    int n = e >> 7, k = e & 127;
    AW2T[e] = f2bf((n < 40 && k < 80) ? aw2[k * 40 + n] : 0.f);
  }
  if (e < 16384) {              // WgP: [64 i][256 t], thread t owns gate col t
    int i = e >> 8, tt = e & 255;
    int row = 128 + 2 * i;
    WgP1[e] = pkf16(Wg1[row * 256 + tt], Wg1[(row + 1) * 256 + tt]);
    WgP2[e] = pkf16(Wg2[row * 256 + tt], Wg2[(row + 1) * 256 + tt]);
  }
  if (e < 8192) {               // WcP: [32 i][256 t], thread t: col t>>1, half t&1
    int i = e >> 8, tt = e & 255;
    int jc = tt >> 1, half = tt & 1;
    int row = 128 + half * 64 + 2 * i;
    WcP1[e] = pkf16(Wc1[row * 128 + jc], Wc1[(row + 1) * 128 + jc]);
    WcP2[e] = pkf16(Wc2[row * 128 + jc], Wc2[(row + 1) * 128 + jc]);
  }
  if (e < 384) {
    b384_1[e] = (e < 256) ? bg1[e] : bc1[e - 256];
    b384_2[e] = (e < 256) ? bg2[e] : bc2[e - 256];
  }
  if (e < 128) {
    bA1[e] = (e < 80) ? ab1[e] : 0.f;
    bA2[e] = (e < 40) ? ab2[e] : 0.f;
    w3p[e] = (e < 40) ? aw3[e] : 0.f;
  }
}

// ---------------------------------------------------------------- cast his -> bf16 t-major
__global__ __launch_bounds__(256) void cast_his_t(const float4* __restrict__ in4,
                                                  ushort4* __restrict__ out4)
{
  int i = blockIdx.x * 256 + threadIdx.x;
  float4 v = in4[i];
  int d4 = (i & 31) << 2;
  int bt = i >> 5;
  int tt = bt % 200, bb = bt / 200;
  out4[(((size_t)tt * 512 + bb) * 128 + d4) >> 2] =
      make_ushort4(f2bf(v.x), f2bf(v.y), f2bf(v.z), f2bf(v.w));
}

// ---------------------------------------------------------------- gemm body
// SRC 0: plain bf16 A. SRC 1: din on-the-fly [q|r|q-r|q*r], K=512.
// EPI 0: f16 out (+bias). EPI 1: bf16 sigmoid out. EPI 2: sigmoid+scorer->scores.
struct GemmP {
  const unsigned short* A;
  const unsigned short* B;
  const float* bias;
  unsigned short* out;
  float* scores;
  const float* w3p;
  const float* b3;
  const unsigned short* Xq;
  const unsigned short* rnn1;
  long rowbase;
  int K, ldc, mtiles, tbase;
};

static __device__ __forceinline__ uint4 bfop(uint4 q, uint4 r, bool mul) {
  unsigned short* qs = (unsigned short*)&q;
  unsigned short* rs = (unsigned short*)&r;
  uint4 o;
  unsigned short* os = (unsigned short*)&o;
#pragma unroll
  for (int i = 0; i < 8; i++) {
    float a = bf2f(qs[i]), b = bf2f(rs[i]);
    os[i] = f2bf(mul ? a * b : a - b);
  }
  return o;
}

template <int SRC, int EPI>
__device__ __forceinline__ void gemm_body(const GemmP& P, int tile, char* smem) {
  uint4* AsB = (uint4*)smem;         // 16 KB
  uint4* BsB = AsB + 1024;           // 16 KB
  const int tid = threadIdx.x;
  const int w = tid >> 6, l = tid & 63;
  const int mb = tile % P.mtiles, nb = tile / P.mtiles;
  const long mBase = (long)mb * 128;
  const int nBase = nb * 128;

  f32x4 acc[2][8];
#pragma unroll
  for (int m = 0; m < 2; m++)
#pragma unroll
    for (int n = 0; n < 8; n++) acc[m][n] = 0.f;

  const int srow = (tid >> 3) & 31;
  const int scc = l & 7;
  const int KK = SRC ? 512 : P.K;

  for (int kb = 0; kb < KK; kb += 64) {
#pragma unroll
    for (int p = 0; p < 4; p++) {
      int row = p * 32 + srow;
      long grow = mBase + row;
      uint4 va;
      if (SRC == 0) {
        va = *(const uint4*)(P.A + (size_t)grow * KK + kb + scc * 8);
      } else {
        int seg = kb >> 7;
        int c0 = (kb & 127) + scc * 8;
        int b = (int)(grow & 511);
        if (seg == 0) {
          va = *(const uint4*)(P.Xq + b * 128 + c0);
        } else if (seg == 1) {
          va = *(const uint4*)(P.rnn1 + (size_t)(P.rowbase + grow) * 128 + c0);
        } else {
          uint4 vq = *(const uint4*)(P.Xq + b * 128 + c0);
          uint4 vr = *(const uint4*)(P.rnn1 + (size_t)(P.rowbase + grow) * 128 + c0);
          va = bfop(vq, vr, seg == 3);
        }
      }
      uint4 vb = *(const uint4*)(P.B + (size_t)(nBase + row) * KK + kb + scc * 8);
      AsB[row * 8 + (scc ^ (row & 7))] = va;
      BsB[row * 8 + (scc ^ (row & 7))] = vb;
    }
    __syncthreads();
#pragma unroll
    for (int ks = 0; ks < 2; ks++) {
      int ccr = ks * 4 + (l >> 4);
      int r0 = w * 32 + (l & 15);
      int r1 = r0 + 16;
      bf16x8 a0 = *(const bf16x8*)&AsB[r0 * 8 + (ccr ^ (r0 & 7))];
      bf16x8 a1 = *(const bf16x8*)&AsB[r1 * 8 + (ccr ^ (r1 & 7))];
#pragma unroll
      for (int n = 0; n < 8; n++) {
        int rb = n * 16 + (l & 15);
        bf16x8 bn = *(const bf16x8*)&BsB[rb * 8 + (ccr ^ (rb & 7))];
        acc[0][n] = __builtin_amdgcn_mfma_f32_16x16x32_bf16(a0, bn, acc[0][n], 0, 0, 0);
        acc[1][n] = __builtin_amdgcn_mfma_f32_16x16x32_bf16(a1, bn, acc[1][n], 0, 0, 0);
      }
    }
    __syncthreads();
  }

  const int lcol = l & 15, lrow4 = (l >> 4) * 4;
  if (EPI == 2) {
    float sp[2][4] = {{0.f, 0.f, 0.f, 0.f}, {0.f, 0.f, 0.f, 0.f}};
#pragma unroll
    for (int n = 0; n < 8; n++) {
      int gcol = n * 16 + lcol;
      float bb = P.bias[gcol];
      float w3 = P.w3p[gcol];
#pragma unroll
      for (int m = 0; m < 2; m++)
#pragma unroll
        for (int i = 0; i < 4; i++) {
          float v = acc[m][n][i] + bb;
          sp[m][i] += w3 / (1.f + __expf(-v));
        }
    }
#pragma unroll
    for (int msk = 1; msk < 16; msk <<= 1)
#pragma unroll
      for (int m = 0; m < 2; m++)
#pragma unroll
        for (int i = 0; i < 4; i++) sp[m][i] += __shfl_xor(sp[m][i], msk);
    float b3v = P.b3[0];
    if (lcol == 0) {
#pragma unroll
      for (int m = 0; m < 2; m++)
#pragma unroll
        for (int i = 0; i < 4; i++) {
          long grow = mBase + w * 32 + m * 16 + lrow4 + i;
          int b = (int)(grow & 511);
          int tp = (int)(grow >> 9) + P.tbase;
          P.scores[b * 200 + tp] = sp[m][i] + b3v;
        }
    }
  } else {
#pragma unroll
    for (int n = 0; n < 8; n++) {
      int gcol = nBase + n * 16 + lcol;
      float bb = P.bias[gcol];
#pragma unroll
      for (int m = 0; m < 2; m++)
#pragma unroll
        for (int i = 0; i < 4; i++) {
          long grow = mBase + w * 32 + m * 16 + lrow4 + i;
          float v = acc[m][n][i] + bb;
          if (EPI == 0) P.out[grow * P.ldc + gcol] = f2h(v);
          else          P.out[grow * P.ldc + gcol] = f2bf(1.f / (1.f + __expf(-v)));
        }
    }
  }
}

// ---------------------------------------------------------------- gru body
// 1 row/block, 256 threads (r10 structure). Thread t: gate col t; cand col
// t>>1, k-half t&1. Direct f16 scalar LDS writes. Parity-unrolled 2-deep
// prefetch; all global accesses forced to addrspace(1) (vmcnt-only).
struct GruP {
  const unsigned short* xproj;   // f16 [TC][512][384]
  const unsigned int* WgP;       // [64][256]
  const unsigned int* WcP;       // [32][256]
  const int* seqlen;
  const float* alphas;
  unsigned short* outbf;         // bf16 [T][512][128] (GRU1 only)
  float* hstate;
  int tbase;
};

template <int AUGRU>
static __device__ __forceinline__ void gstep(
    const GruP& P, int r, int t, int jc, int half, int len, int ts, int tsn,
    const unsigned int (&wg)[64], const unsigned int (&wc)[32],
    float* hF, float* uF, unsigned short* hH, unsigned short* rgH,
    unsigned short& gX, unsigned short& cX, float& alX)
{
  const unsigned short* xp = P.xproj;
  const size_t RS = (size_t)512 * 384;
  const size_t base = (size_t)r * 384;
  float xg = h2f(gX), xc = h2f(cX), alv = alX;
  size_t off = (size_t)tsn * RS + base;
  gX = gld_u16(xp + off + t);           // reload for step tsn (used 2 steps on)
  cX = gld_u16(xp + off + 256 + jc);
  if (AUGRU) alX = gld_f32(P.alphas + r * 200 + P.tbase + tsn);

  // ---- gates (full col per thread, 4 split chains)
  float a0 = 0.f, a1 = 0.f, a2 = 0.f, a3 = 0.f;
  const uint4* h4 = (const uint4*)hH;
#pragma unroll
  for (int q = 0; q < 4; q++) {
    uint4 h0 = h4[q * 4 + 0];
    uint4 h1 = h4[q * 4 + 1];
    uint4 h2 = h4[q * 4 + 2];
    uint4 h3 = h4[q * 4 + 3];
    dot2a(a0, wg[q * 16 + 0], h0.x);  dot2a(a1, wg[q * 16 + 1], h0.y);
    dot2a(a2, wg[q * 16 + 2], h0.z);  dot2a(a3, wg[q * 16 + 3], h0.w);
    dot2a(a0, wg[q * 16 + 4], h1.x);  dot2a(a1, wg[q * 16 + 5], h1.y);
    dot2a(a2, wg[q * 16 + 6], h1.z);  dot2a(a3, wg[q * 16 + 7], h1.w);
    dot2a(a0, wg[q * 16 + 8], h2.x);  dot2a(a1, wg[q * 16 + 9], h2.y);
    dot2a(a2, wg[q * 16 + 10], h2.z); dot2a(a3, wg[q * 16 + 11], h2.w);
    dot2a(a0, wg[q * 16 + 12], h3.x); dot2a(a1, wg[q * 16 + 13], h3.y);
    dot2a(a2, wg[q * 16 + 14], h3.z); dot2a(a3, wg[q * 16 + 15], h3.w);
  }
  float a = (a0 + a1) + (a2 + a3) + xg;
  float g = 1.f / (1.f + __expf(-a));
  if (t < 128) rgH[t] = f2h(g * hF[t]);
  else         uF[t - 128] = g;
  gbar();

  // ---- candidate + update
  float c0 = 0.f, c1 = 0.f;
  const uint4* rp = (const uint4*)rgH + half * 8;
#pragma unroll
  for (int q = 0; q < 8; q++) {
    uint4 rq = rp[q];
    dot2a(c0, wc[q * 4 + 0], rq.x);
    dot2a(c1, wc[q * 4 + 1], rq.y);
    dot2a(c0, wc[q * 4 + 2], rq.z);
    dot2a(c1, wc[q * 4 + 3], rq.w);
  }
  float c = c0 + c1;
  c += __shfl_xor(c, 1);
  c += xc;
  c = fminf(fmaxf(c, -15.f), 15.f);
  float e2 = __expf(2.f * c);
  c = 1.f - 2.f / (e2 + 1.f);          // tanh
  float u = uF[jc];
  if (AUGRU) u *= (1.f - alv);
  float h = hF[jc];
  float hn = u * h + (1.f - u) * c;
  bool valid = (P.tbase + ts) < len;
  hn = valid ? hn : h;
  if (!half) {
    hF[jc] = hn;
    hH[jc] = f2h(hn);
    if (!AUGRU)
      gst_u16(P.outbf + ((size_t)(P.tbase + ts) * 512 + r) * 128 + jc,
              valid ? f2bf(hn) : (unsigned short)0);
  }
  gbar();
}

template <int AUGRU>
__device__ void gru_body(const GruP& P, int r, char* smem) {
  float* hF = (float*)smem;                           // [128] f32
  float* uF = hF + 128;                               // [128] f32
  unsigned short* hH = (unsigned short*)(uF + 128);   // [128] f16
  unsigned short* rgH = hH + 128;                     // [128] f16
  const int t = threadIdx.x;
  const int jc = t >> 1, half = t & 1;
  const int len = P.seqlen[r];
  int nsteps = len - P.tbase;
  if (nsteps > TC) nsteps = TC;

  if (nsteps <= 0) {
    if (!AUGRU && t < 64) {
      for (int s = 0; s < TC; s++)
        gst_u32((unsigned int*)(P.outbf + ((size_t)(P.tbase + s) * 512 + r) * 128) + t, 0u);
    }
    return;
  }
  __builtin_amdgcn_s_setprio(1);

  unsigned int wg[64], wc[32];
#pragma unroll
  for (int i = 0; i < 64; i++) wg[i] = P.WgP[i * 256 + t];
#pragma unroll
  for (int i = 0; i < 32; i++) wc[i] = P.WcP[i * 256 + t];

  if (t < 128) {
    float h = gld_f32(P.hstate + r * 128 + t);
    hF[t] = h;
    hH[t] = f2h(h);
  }
  gbar();

  const unsigned short* xp = P.xproj;
  const size_t RS = (size_t)512 * 384;
  const size_t base = (size_t)r * 384;
  unsigned short gE = gld_u16(xp + base + t), cE = gld_u16(xp + base + 256 + jc);
  int s1 = nsteps > 1 ? 1 : 0;
  unsigned short gO = gld_u16(xp + s1 * RS + base + t);
  unsigned short cO = gld_u16(xp + s1 * RS + base + 256 + jc);
  float alE = AUGRU ? gld_f32(P.alphas + r * 200 + P.tbase) : 0.f;
  float alO = AUGRU ? gld_f32(P.alphas + r * 200 + P.tbase + s1) : 0.f;

  int rsteps = (nsteps + 1) & ~1;      // even (TC=50 is even; masked extra step ok)
  for (int ts = 0; ts < rsteps; ts += 2) {
    int tn0 = (ts + 2 < nsteps) ? ts + 2 : nsteps - 1;
    int tn1 = (ts + 3 < nsteps) ? ts + 3 : nsteps - 1;
    gstep<AUGRU>(P, r, t, jc, half, len, ts,     tn0, wg, wc, hF, uF, hH, rgH, gE, cE, alE);
    gstep<AUGRU>(P, r, t, jc, half, len, ts + 1, tn1, wg, wc, hF, uF, hH, rgH, gO, cO, alO);
  }

  if (t < 128) gst_f32(P.hstate + r * 128 + t, hF[t]);
  if (!AUGRU && t < 64) {
    for (int s = rsteps; s < TC; s++)
      gst_u32((unsigned int*)(P.outbf + ((size_t)(P.tbase + s) * 512 + r) * 128) + t, 0u);
  }
}

// ---------------------------------------------------------------- his_sum body
__device__ void hsum_body(const float* __restrict__ his, float* __restrict__ hs,
                          const int* __restrict__ seqlen, int b, char* smem) {
  float* sm = (float*)smem;
  int t = threadIdx.x;
  int len = seqlen[b];
  int col = t & 127, hf = t >> 7;
  float s = 0.f;
  for (int ts = hf; ts < len; ts += 2) s += his[((size_t)b * 200 + ts) * 128 + col];
  sm[t] = s;
  __syncthreads();
  if (t < 128) hs[b * 128 + t] = sm[t] + sm[t + 128];
}

// ---------------------------------------------------------------- fat kernel
template <int AUG, int GRU, int S1, int E1, int S2, int E2, int S3, int E3, int HS>
__global__ __launch_bounds__(256) void fatk(GruP gp, GemmP p1, int c1,
                                            GemmP p2, int c2, GemmP p3,
                                            const float* hisp, float* hsp)
{
  extern __shared__ char smem[];
  int id = blockIdx.x;
  if constexpr (GRU) {
    if (id < 512) { gru_body<AUG>(gp, id, smem); return; }
    id -= 512;
  }
  if constexpr (HS) {
    if (id < 512) { hsum_body(hisp, hsp, gp.seqlen, id, smem); return; }
    id -= 512;
  }
  if constexpr (S1 >= 0) {
    if (id < c1) { gemm_body<S1, E1>(p1, id, smem); return; }
    id -= c1;
  }
  if constexpr (S2 >= 0) {
    if (id < c2) { gemm_body<S2, E2>(p2, id, smem); return; }
    id -= c2;
  }
  if constexpr (S3 >= 0) gemm_body<S3, E3>(p3, id, smem);
}

// ---------------------------------------------------------------- masked softmax (+zero hstate)
__global__ __launch_bounds__(256) void mask_softmax(
    const float* __restrict__ scores, const int* __restrict__ seqlen,
    float* __restrict__ alphas, float* __restrict__ hstate)
{
  int b = blockIdx.x, t = threadIdx.x;
  __shared__ float red[256];
  if (t < 128) hstate[b * 128 + t] = 0.f;
  int len = seqlen[b];
  float s = (t < 200 && t < len) ? scores[b * 200 + t] : -1e30f;
  red[t] = s;
  __syncthreads();
  for (int o = 128; o > 0; o >>= 1) {
    if (t < o) red[t] = fmaxf(red[t], red[t + o]);
    __syncthreads();
  }
  float m = red[0];
  __syncthreads();
  float e = (t < 200 && t < len) ? __expf(s - m) : 0.f;
  red[t] = e;
  __syncthreads();
  for (int o = 128; o > 0; o >>= 1) {
    if (t < o) red[t] += red[t + o];
    __syncthreads();
  }
  float denom = red[0];
  if (t < 200) alphas[b * 200 + t] = e / denom;
}

// ---------------------------------------------------------------- head (his_sum precomputed)
__global__ __launch_bounds__(256) void head_kernel(
    const float* __restrict__ item_eb, const float* __restrict__ hs,
    const float* __restrict__ hstate,
    const float* __restrict__ w1, const float* __restrict__ b1, const float* __restrict__ a1,
    const float* __restrict__ w2, const float* __restrict__ b2, const float* __restrict__ a2,
    const float* __restrict__ w3, const float* __restrict__ b3,
    float* __restrict__ out)
{
  int b = blockIdx.x, t = threadIdx.x;
  __shared__ float frow[512];
  __shared__ float z1[200];
  __shared__ float z2[80];
  if (t < 128) {
    float sv = hs[b * 128 + t];
    float q = item_eb[b * 128 + t];
    frow[t] = q;
    frow[128 + t] = sv;
    frow[256 + t] = q * sv;
    frow[384 + t] = hstate[b * 128 + t];
  }
  __syncthreads();
  if (t < 200) {
    float acc = b1[t];
#pragma unroll 8
    for (int k = 0; k < 512; k++) acc += frow[k] * w1[k * 200 + t];
    z1[t] = acc > 0.f ? acc : a1[t] * acc;
  }
  __syncthreads();
  if (t < 80) {
    float acc = b2[t];
#pragma unroll 8
    for (int k = 0; k < 200; k++) acc += z1[k] * w2[k * 80 + t];
    z2[t] = acc > 0.f ? acc : a2[t] * acc;
  }
  __syncthreads();
  if (t == 0) {
    float l0 = b3[0], l1 = b3[1];
    for (int k = 0; k < 80; k++) {
      float z = z2[k];
      l0 += z * w3[k * 2];
      l1 += z * w3[k * 2 + 1];
    }
    float m = fmaxf(l0, l1);
    float e0 = __expf(l0 - m), e1 = __expf(l1 - m);
    out[b * 2 + 0] = e0 / (e0 + e1);
    out[b * 2 + 1] = e1 / (e0 + e1);
  }
}

// ---------------------------------------------------------------- launch
extern "C" void kernel_launch(void* const* d_in, const int* in_sizes, int n_in,
                              void* d_out, int out_size, void* d_ws, size_t ws_size,
                              hipStream_t stream)
{
  const float* item_eb = (const float*)d_in[0];
  const float* his     = (const float*)d_in[1];
  const float* Wg1     = (const float*)d_in[2];
  const float* bg1     = (const float*)d_in[3];
  const float* Wc1     = (const float*)d_in[4];
  const float* bc1     = (const float*)d_in[5];
  const float* aw1     = (const float*)d_in[6];
  const float* ab1     = (const float*)d_in[7];
  const float* aw2     = (const float*)d_in[8];
  const float* ab2     = (const float*)d_in[9];
  const float* aw3     = (const float*)d_in[10];
  const float* ab3     = (const float*)d_in[11];
  const float* Wg2     = (const float*)d_in[12];
  const float* bg2     = (const float*)d_in[13];
  const float* Wc2     = (const float*)d_in[14];
  const float* bc2     = (const float*)d_in[15];
  const float* fc1w    = (const float*)d_in[16];
  const float* fc1b    = (const float*)d_in[17];
  const float* al1     = (const float*)d_in[18];
  const float* fc2w    = (const float*)d_in[19];
  const float* fc2b    = (const float*)d_in[20];
  const float* al2     = (const float*)d_in[21];
  const float* fc3w    = (const float*)d_in[22];
  const float* fc3b    = (const float*)d_in[23];
  const int*   seqlen  = (const int*)d_in[24];

  // ---- workspace layout (~93.5 MB; round-2 proved >=94.24 MB available)
  char* ws = (char*)d_ws;
  unsigned short* XhA    = (unsigned short*)(ws + 0L);         // 26,214,400 his bf16 t-major; later h1 ring
  unsigned short* xpA    = (unsigned short*)(ws + 26214400L);  // 19,660,800 f16 xproj buf A
  unsigned short* xpB    = (unsigned short*)(ws + 45875200L);  // 19,660,800 f16 xproj buf B
  unsigned short* rnn1   = (unsigned short*)(ws + 65536000L);  // 26,214,400
  float*          scores = (float*)(ws + 91750400L);           //    409,600 (hs after softmax)
  float*          alphas = (float*)(ws + 92160000L);           //    409,600
  float*          hstate = (float*)(ws + 92569600L);           //    262,144
  unsigned int*   WgP1   = (unsigned int*)(ws + 92831744L);    //     65,536
  unsigned int*   WcP1   = (unsigned int*)(ws + 92897280L);    //     32,768
  unsigned int*   WgP2   = (unsigned int*)(ws + 92930048L);    //     65,536
  unsigned int*   WcP2   = (unsigned int*)(ws + 92995584L);    //     32,768
  unsigned short* W1xT   = (unsigned short*)(ws + 93028352L);  //     98,304
  unsigned short* W2xT   = (unsigned short*)(ws + 93126656L);  //     98,304
  unsigned short* AW1T   = (unsigned short*)(ws + 93224960L);  //    131,072
  unsigned short* AW2T   = (unsigned short*)(ws + 93356032L);  //     32,768
  float*          b384_1 = (float*)(ws + 93388800L);           //      1,536
  float*          b384_2 = (float*)(ws + 93390336L);           //      1,536
  float*          bA1    = (float*)(ws + 93391872L);           //        512
  float*          bA2    = (float*)(ws + 93392384L);           //        512
  float*          w3p    = (float*)(ws + 93392896L);           //        512
  unsigned short* Xq     = (unsigned short*)(ws + 93393408L);  //    131,072
  float*          hs     = scores;                             // reuse after softmax

  unsigned short* h1[NC] = {XhA, XhA + CSH, XhA + 2 * CSH, XhA + 3 * CSH};

  const int SM = 32768;
  GruP gz{}; GemmP dz{};
  gz.seqlen = seqlen;

  auto mkGru = [&](int c, int aug) {
    GruP g;
    g.xproj = (c & 1) ? xpB : xpA;
    g.WgP = aug ? WgP2 : WgP1; g.WcP = aug ? WcP2 : WcP1;
    g.seqlen = seqlen; g.alphas = alphas;
    g.outbf = aug ? nullptr : rnn1; g.hstate = hstate; g.tbase = c * TC;
    return g;
  };
  auto mkXp = [&](const unsigned short* A, const float* bias, unsigned short* outp) {
    GemmP p{}; p.A = A; p.B = (bias == b384_1) ? W1xT : W2xT; p.bias = bias;
    p.out = outp; p.K = 128; p.ldc = 384; p.mtiles = 200; return p;
  };
  auto mkAtt1 = [&](int c) {
    GemmP p{}; p.B = AW1T; p.bias = bA1; p.out = h1[c];
    p.Xq = Xq; p.rnn1 = rnn1; p.rowbase = (long)c * CROWS;
    p.K = 512; p.ldc = 128; p.mtiles = 200; return p;
  };
  auto mkAtt2 = [&](int c) {
    GemmP p{}; p.A = h1[c]; p.B = AW2T; p.bias = bA2;
    p.scores = scores; p.w3p = w3p; p.b3 = ab3;
    p.K = 128; p.ldc = 128; p.mtiles = 200; p.tbase = c * TC; return p;
  };

  // L1/L2: prep + cast
  prep_weights<<<256, 256, 0, stream>>>(item_eb, Wg1, Wc1, Wg2, Wc2, aw1, aw2, aw3,
                                        bg1, bc1, bg2, bc2, ab1, ab2,
                                        W1xT, W2xT, AW1T, AW2T, b384_1, b384_2, bA1, bA2,
                                        WgP1, WcP1, WgP2, WcP2, w3p, Xq, hstate);
  cast_his_t<<<12800, 256, 0, stream>>>((const float4*)his, (ushort4*)XhA);

  // L3: xproj1-c0 -> xpA
  fatk<0,0, 0,0, -1,0, -1,0, 0><<<600, 256, SM, stream>>>(
      gz, mkXp(XhA, b384_1, xpA), 600, dz, 0, dz, nullptr, nullptr);
  // L4: gru1-c0 | xproj1-c1 -> xpB
  fatk<0,1, 0,0, -1,0, -1,0, 0><<<1112, 256, SM, stream>>>(
      mkGru(0,0), mkXp(XhA + (size_t)CSH, b384_1, xpB), 600, dz, 0, dz, nullptr, nullptr);
  // L5: gru1-c1 | xproj1-c2 -> xpA
  fatk<0,1, 0,0, -1,0, -1,0, 0><<<1112, 256, SM, stream>>>(
      mkGru(1,0), mkXp(XhA + (size_t)2*CSH, b384_1, xpA), 600, dz, 0, dz, nullptr, nullptr);
  // L6: gru1-c2 | xproj1-c3 -> xpB | att1-c0 -> h1[0]
  fatk<0,1, 0,0, 1,1, -1,0, 0><<<1712, 256, SM, stream>>>(
      mkGru(2,0), mkXp(XhA + (size_t)3*CSH, b384_1, xpB), 600, mkAtt1(0), 200, dz, nullptr, nullptr);
  // L7: gru1-c3 | att1-c1 | att2-c0
  fatk<0,1, 1,1, 0,2, -1,0, 0><<<912, 256, SM, stream>>>(
      mkGru(3,0), mkAtt1(1), 200, mkAtt2(0), 200, dz, nullptr, nullptr);
  // L8: att1-c2 | att2-c1 | augru-gemm-c0 -> xpA
  fatk<0,0, 1,1, 0,2, 0,0, 0><<<1000, 256, SM, stream>>>(
      gz, mkAtt1(2), 200, mkAtt2(1), 200, mkXp(rnn1, b384_2, xpA), nullptr, nullptr);
  // L9: att1-c3 | att2-c2 | augru-gemm-c1 -> xpB
  fatk<0,0, 1,1, 0,2, 0,0, 0><<<1000, 256, SM, stream>>>(
      gz, mkAtt1(3), 200, mkAtt2(2), 200, mkXp(rnn1 + (size_t)CSH, b384_2, xpB), nullptr, nullptr);
  // L10: att2-c3
  fatk<0,0, 0,2, -1,0, -1,0, 0><<<200, 256, SM, stream>>>(
      gz, mkAtt2(3), 200, dz, 0, dz, nullptr, nullptr);
  // L11: softmax + zero hstate
  mask_softmax<<<512, 256, 0, stream>>>(scores, seqlen, alphas, hstate);
  // L12: augru-c0 | his_sum backfill
  fatk<1,1, -1,0, -1,0, -1,0, 1><<<1024, 256, SM, stream>>>(
      mkGru(0,1), dz, 0, dz, 0, dz, his, hs);
  // L13: augru-c1 | augru-gemm-c2 -> xpA
  fatk<1,1, 0,0, -1,0, -1,0, 0><<<1112, 256, SM, stream>>>(
      mkGru(1,1), mkXp(rnn1 + (size_t)2*CSH, b384_2, xpA), 600, dz, 0, dz, nullptr, nullptr);
  // L14: augru-c2 | augru-gemm-c3 -> xpB
  fatk<1,1, 0,0, -1,0, -1,0, 0><<<1112, 256, SM, stream>>>(
      mkGru(2,1), mkXp(rnn1 + (size_t)3*CSH, b384_2, xpB), 600, dz, 0, dz, nullptr, nullptr);
  // L15: augru-c3
  fatk<1,1, -1,0, -1,0, -1,0, 0><<<512, 256, SM, stream>>>(
      mkGru(3,1), dz, 0, dz, 0, dz, nullptr, nullptr);
  // L16: head
  head_kernel<<<512, 256, 0, stream>>>(item_eb, hs, hstate,
                                       fc1w, fc1b, al1, fc2w, fc2b, al2,
                                       fc3w, fc3b, (float*)d_out);
}